// Round 1
// baseline (278.954 us; speedup 1.0000x reference)
//
#include <hip/hip_runtime.h>

// Problem constants (from reference file)
#define N_NODES 100000
#define F_DIM   32
#define D_DIM   3
#define O_DIM   32
#define E_EDGES 1600000

// Kernel 1: per-edge gaussian weighting + gather x[col] + scatter-add into acc[row].
// Layout: each 32-thread group handles one edge; lane-within-group = channel f.
// Per-channel mu/sigma constants are loaded once per thread (registers),
// amortized over the grid-stride loop over edges.
__global__ void gmm_edge_scatter(const float* __restrict__ x,
                                 const int*   __restrict__ edge_index,
                                 const float* __restrict__ pseudo,
                                 const float* __restrict__ mu,
                                 const float* __restrict__ sigma,
                                 float* __restrict__ acc) {
    const int f = threadIdx.x & 31;

    // per-channel constants (F=32, D=3), cached in registers
    const float m0 = mu[f * 3 + 0];
    const float m1 = mu[f * 3 + 1];
    const float m2 = mu[f * 3 + 2];
    const float s0 = sigma[f * 3 + 0];
    const float s1 = sigma[f * 3 + 1];
    const float s2 = sigma[f * 3 + 2];
    const float c0 = 0.5f / (1e-14f + s0 * s0);
    const float c1 = 0.5f / (1e-14f + s1 * s1);
    const float c2 = 0.5f / (1e-14f + s2 * s2);

    int group   = (blockIdx.x * blockDim.x + threadIdx.x) >> 5;
    int ngroups = (gridDim.x * blockDim.x) >> 5;

    for (int e = group; e < E_EDGES; e += ngroups) {
        // edge_index is (2, E): row at [e], col at [E + e]
        const int row = edge_index[e];
        const int col = edge_index[E_EDGES + e];

        // pseudo[e] : 3 floats; all 32 lanes of the group read the same
        // 12 bytes -> single cache line, L1 broadcast.
        const float p0 = pseudo[e * 3 + 0];
        const float p1 = pseudo[e * 3 + 1];
        const float p2 = pseudo[e * 3 + 2];

        const float d0 = p0 - m0;
        const float d1 = p1 - m1;
        const float d2 = p2 - m2;
        const float lw = -(c0 * d0 * d0 + c1 * d1 * d1 + c2 * d2 * d2);
        const float g  = __expf(lw);

        // coalesced 128B gather of x row
        const float v = x[col * F_DIM + f] * g;

        atomicAdd(&acc[row * F_DIM + f], v);
    }
}

// Kernel 2: out(N,32) = acc(N,32) @ W^T(32,32) + b
// W staged transposed into LDS (Wt[f*32+o]) so lane o hits bank o: conflict-free.
// acc row broadcast across the 32-lane group via __shfl(width=32).
__global__ void gmm_linear(const float* __restrict__ acc,
                           const float* __restrict__ W,
                           const float* __restrict__ b,
                           float* __restrict__ out) {
    __shared__ float Wt[F_DIM * O_DIM];  // Wt[f*32 + o] = W[o*32 + f]
    __shared__ float bs[O_DIM];

    for (int i = threadIdx.x; i < O_DIM * F_DIM; i += blockDim.x) {
        const int o = i >> 5;    // i / F_DIM
        const int f = i & 31;    // i % F_DIM
        Wt[f * O_DIM + o] = W[i];
    }
    if (threadIdx.x < O_DIM) bs[threadIdx.x] = b[threadIdx.x];
    __syncthreads();

    const int o       = threadIdx.x & 31;
    int       n       = (blockIdx.x * blockDim.x + threadIdx.x) >> 5;
    const int nstride = (gridDim.x * blockDim.x) >> 5;

    for (; n < N_NODES; n += nstride) {
        const float a = acc[n * F_DIM + o];  // coalesced; lane o holds acc[n][o]
        float s = bs[o];
#pragma unroll
        for (int f = 0; f < F_DIM; ++f) {
            const float af = __shfl(a, f, 32);   // broadcast acc[n][f] to all lanes
            s += af * Wt[f * O_DIM + o];
        }
        out[n * O_DIM + o] = s;
    }
}

extern "C" void kernel_launch(void* const* d_in, const int* in_sizes, int n_in,
                              void* d_out, int out_size, void* d_ws, size_t ws_size,
                              hipStream_t stream) {
    const float* x          = (const float*)d_in[0];
    const int*   edge_index = (const int*)  d_in[1];
    const float* pseudo     = (const float*)d_in[2];
    const float* mu         = (const float*)d_in[3];
    const float* sigma      = (const float*)d_in[4];
    const float* W          = (const float*)d_in[5];
    const float* b          = (const float*)d_in[6];
    float*       out        = (float*)d_out;

    float* acc = (float*)d_ws;  // N_NODES * F_DIM floats = 12.8 MB

    hipMemsetAsync(acc, 0, (size_t)N_NODES * F_DIM * sizeof(float), stream);

    // Stage 1: edge scatter. 4096 blocks x 256 threads = 32768 edge-groups,
    // ~49 grid-stride iterations over 1.6M edges.
    gmm_edge_scatter<<<4096, 256, 0, stream>>>(x, edge_index, pseudo, mu, sigma, acc);

    // Stage 2: linear. 100000 rows * 32 outs / (256/32 rows per block) = 12500 blocks max;
    // grid-stride with 4096 blocks.
    gmm_linear<<<4096, 256, 0, stream>>>(acc, W, b, out);
}